// Round 11
// baseline (242.416 us; speedup 1.0000x reference)
//
#include <hip/hip_runtime.h>
#include <hip/hip_bf16.h>

// Gram matrix: G = X @ X^T, X = [512, 65536] fp32, out = [512, 512] fp32.
// Round 21 = Round 20 RERUN (bench infra failed twice; hypothesis untested).
// r19 confirmed delivery rate is SATURATED (~9.4 B/cyc/CU = ~5.9 TB/s):
// occupancy 22->34% moved nothing; gram = issued_bytes / 5.9 TB/s predicts
// r17/r18/r19 within 2%. So cut ISSUED BYTES with the engine byte-identical:
// PAIR each diag tile with an off-diag tile sharing a panel.
//   6 block types: {(0,0)+(0,1)},{(1,1)+(1,2)},{(2,2)+(2,3)},{(3,3)+(0,3)}
//   (2 panels -> 2 tiles) + {(0,2)},{(1,3)} (2 panels -> 1 tile).
//   12 panel-streams instead of 16: 512 -> 384 MB issued (-25%).
//   Every block stages two [128][40] bf16 panels exactly like r10 (8 float4
//   per thread); pair blocks run 32 MFMA/iter instead of 16 (MfmaUtil 9->16%,
//   huge headroom). acc[2][4][4] = 128 VGPR -> ~240 total, 2 blocks/CU.
//   KC=512, grid 768 (pair types 0-3 = heavy, launched first).
//   Slabs: tile_id*128+chunk -> same 1280-slab/84MB layout as r19; reduce
//   kernel reused verbatim. Fallback: r17 atomic path if ws too small.
// Tripwire: VGPR=256+scratch -> spill; retry as 512-thread variant.
// Pre-commit: gram >=85us with clean VGPR -> byte lever exhausted -> roofline.
// History: r1 135; r10 100; r17 98.3; r18 90.4 (bench 227.9 best); r19 88.6
// (bench 232.9); r20 infra-failed (this code, unmeasured).

typedef short bf16x8 __attribute__((ext_vector_type(8)));   // 8 bf16 = 4 VGPRs
typedef float f32x4  __attribute__((ext_vector_type(4)));   // MFMA acc

#define HW    65536
#define CDIM  512
#define LDSS  40            // panel stride in shorts (r10 proven)
#define TILE_ELEMS 16384    // 128*128

__device__ __forceinline__ short f2bf(float f) {
    __hip_bfloat16 h = __float2bfloat16(f);   // RNE
    short s;
    __builtin_memcpy(&s, &h, sizeof(short));
    return s;
}

__device__ __forceinline__ bf16x8 cvt8(float4 a, float4 b) {
    bf16x8 v;
    v[0] = f2bf(a.x); v[1] = f2bf(a.y); v[2] = f2bf(a.z); v[3] = f2bf(a.w);
    v[4] = f2bf(b.x); v[5] = f2bf(b.y); v[6] = f2bf(b.z); v[7] = f2bf(b.w);
    return v;
}

// ---------------- pair kernel: 2 panels -> up to 2 tiles ----------------
// p = type*128 + chunk; KC=512 (16 iters of BK=32).
// type: SA = panel staged in As, SB = panel staged in Bs.
//   0..3: diag (SA,SA) + off; 4..5: off only.
//   off tile: types 0-2,4,5 = (SA,SB) via mfma(As@a, Bs@b);
//             type 3        = (SB,SA) via mfma(Bs@a, As@b).
__global__ __launch_bounds__(256, 2)
void gram_pair_kernel(const float* __restrict__ X, float* __restrict__ ws) {
    const int p     = blockIdx.x;        // 0..767
    const int type  = p >> 7;            // 0..5
    const int chunk = p & 127;
    const int kbase = chunk << 9;        // *512

    const int SA[6]      = {0, 1, 2, 3, 0, 1};
    const int SB[6]      = {1, 2, 3, 0, 2, 3};
    const int OFFSLAB[6] = {0, 3, 5, 2, 1, 4};   // tile ids in reduce's list
    const int sa = SA[type], sb = SB[type];
    const bool hasd = (type < 4);
    const bool swap = (type == 3);

    __shared__ short As[128 * LDSS];
    __shared__ short Bs[128 * LDSS];

    const int t    = threadIdx.x;
    const int wave = t >> 6;
    const int lane = t & 63;
    const int wm   = wave & 1;          // 2x2 wave grid, each wave = 64x64
    const int wn   = wave >> 1;

    // --- staging (r10 byte-identical): 2 threads/row, 16 consecutive fp32 ---
    const int srow  = t >> 1;           // 0..127
    const int shalf = (t & 1) * 16;     // k offset 0 or 16
    const float* pa = X + (size_t)(sa * 128 + srow) * HW + kbase + shalf;
    const float* pb = X + (size_t)(sb * 128 + srow) * HW + kbase + shalf;
    short* wa = As + srow * LDSS + shalf;
    short* wb = Bs + srow * LDSS + shalf;

    // --- fragment read offsets ---
    const int fm = lane & 15;
    const int kg = lane >> 4;           // 0..3, each group = 8 contiguous k
    int a_off[4], b_off[4];
#pragma unroll
    for (int i = 0; i < 4; ++i) {
        a_off[i] = (wm * 64 + i * 16 + fm) * LDSS + kg * 8;
        b_off[i] = (wn * 64 + i * 16 + fm) * LDSS + kg * 8;
    }

    f32x4 acc0[4][4], acc1[4][4];       // diag tile, off tile
#pragma unroll
    for (int i = 0; i < 4; ++i)
#pragma unroll
        for (int j = 0; j < 4; ++j) {
            acc0[i][j] = (f32x4){0.f, 0.f, 0.f, 0.f};
            acc1[i][j] = (f32x4){0.f, 0.f, 0.f, 0.f};
        }

    for (int it = 0; it < 16; ++it) {
        float4 a0 = *(const float4*)(pa + 0);
        float4 a1 = *(const float4*)(pa + 4);
        float4 a2 = *(const float4*)(pa + 8);
        float4 a3 = *(const float4*)(pa + 12);
        float4 b0 = *(const float4*)(pb + 0);
        float4 b1 = *(const float4*)(pb + 4);
        float4 b2 = *(const float4*)(pb + 8);
        float4 b3 = *(const float4*)(pb + 12);

        bf16x8 va0 = cvt8(a0, a1), va1 = cvt8(a2, a3);
        bf16x8 vb0 = cvt8(b0, b1), vb1 = cvt8(b2, b3);

        __syncthreads();   // prior iteration's LDS reads complete
        *(bf16x8*)(wa + 0) = va0;
        *(bf16x8*)(wa + 8) = va1;
        *(bf16x8*)(wb + 0) = vb0;
        *(bf16x8*)(wb + 8) = vb1;
        __syncthreads();   // stage visible to all waves

        // fragment sets: fa = As@a_off, gb = As@b_off (diag / type-3 off),
        //                hb = Bs@(swap ? a_off : b_off)
        bf16x8 fa[4], gb[4], hb[4];
#pragma unroll
        for (int i = 0; i < 4; ++i) fa[i] = *(const bf16x8*)(As + a_off[i]);
#pragma unroll
        for (int j = 0; j < 4; ++j)
            hb[j] = *(const bf16x8*)(Bs + (swap ? a_off[j] : b_off[j]));
        if (hasd) {
#pragma unroll
            for (int j = 0; j < 4; ++j) gb[j] = *(const bf16x8*)(As + b_off[j]);
            // diag tile (SA,SA)
#pragma unroll
            for (int i = 0; i < 4; ++i)
#pragma unroll
                for (int j = 0; j < 4; ++j)
                    acc0[i][j] = __builtin_amdgcn_mfma_f32_16x16x32_bf16(
                        fa[i], gb[j], acc0[i][j], 0, 0, 0);
        }
        // off tile
        if (!swap) {
#pragma unroll
            for (int i = 0; i < 4; ++i)
#pragma unroll
                for (int j = 0; j < 4; ++j)
                    acc1[i][j] = __builtin_amdgcn_mfma_f32_16x16x32_bf16(
                        fa[i], hb[j], acc1[i][j], 0, 0, 0);
        } else {
#pragma unroll
            for (int i = 0; i < 4; ++i)
#pragma unroll
                for (int j = 0; j < 4; ++j)
                    acc1[i][j] = __builtin_amdgcn_mfma_f32_16x16x32_bf16(
                        hb[i], gb[j], acc1[i][j], 0, 0, 0);
        }

        pa += 32;
        pb += 32;
    }

    // --- epilogue: streaming stores into private slabs (r18 pattern) ---
    // C/D layout (verified m89/m91): col = lane&15, row = (lane>>4)*4 + reg
    const int lrow0 = wm * 64 + (lane >> 4) * 4;
    const int lcol0 = wn * 64 + fm;
    if (hasd) {
        float* slab0 = ws + ((size_t)(6 + sa) * 128 + chunk) * TILE_ELEMS;
#pragma unroll
        for (int i = 0; i < 4; ++i)
#pragma unroll
            for (int j = 0; j < 4; ++j)
#pragma unroll
                for (int r = 0; r < 4; ++r)
                    slab0[(lrow0 + i * 16 + r) * 128 + lcol0 + j * 16] =
                        acc0[i][j][r];
    }
    float* slab1 = ws + ((size_t)OFFSLAB[type] * 128 + chunk) * TILE_ELEMS;
#pragma unroll
    for (int i = 0; i < 4; ++i)
#pragma unroll
        for (int j = 0; j < 4; ++j)
#pragma unroll
            for (int r = 0; r < 4; ++r)
                slab1[(lrow0 + i * 16 + r) * 128 + lcol0 + j * 16] =
                    acc1[i][j][r];
}

// ------- reduce (r19 verbatim, CSH=7): sum 128 partials, write out + mirror -------
__global__ __launch_bounds__(128)
void reduce_kernel(const float* __restrict__ ws, float* __restrict__ out) {
    const int gid = blockIdx.x * 128 + threadIdx.x;    // 0..40959
    const int tt  = gid >> 12;                         // tile 0..9
    const int e4  = (gid & 4095) << 2;                 // element base 0..16380
    const int TI[10] = {0, 0, 0, 1, 1, 2, 0, 1, 2, 3};
    const int TJ[10] = {1, 2, 3, 2, 3, 3, 0, 1, 2, 3};
    const int ti = TI[tt], tj = TJ[tt];
    const float* base = ws + ((size_t)tt << 7) * TILE_ELEMS + e4;

    f32x4 s0 = {0.f, 0.f, 0.f, 0.f}, s1 = s0, s2 = s0, s3 = s0;
#pragma unroll 4
    for (int c = 0; c < 128; c += 4) {     // 4 independent chains (MLP)
        s0 += *(const f32x4*)(base + (size_t)(c + 0) * TILE_ELEMS);
        s1 += *(const f32x4*)(base + (size_t)(c + 1) * TILE_ELEMS);
        s2 += *(const f32x4*)(base + (size_t)(c + 2) * TILE_ELEMS);
        s3 += *(const f32x4*)(base + (size_t)(c + 3) * TILE_ELEMS);
    }
    const f32x4 s = (s0 + s1) + (s2 + s3);

    const int r0 = e4 >> 7;                // row in tile 0..127
    const int c0 = e4 & 127;               // col base in tile
    *(f32x4*)(out + (ti * 128 + r0) * CDIM + tj * 128 + c0) = s;
    if (tt < 6) {                          // mirror upper tiles
#pragma unroll
        for (int k = 0; k < 4; ++k)
            out[(tj * 128 + c0 + k) * CDIM + ti * 128 + r0] = s[k];
    }
}

// ---------------- fallback: r17's proven atomic path ----------------
__global__ __launch_bounds__(256, 2)
void gram_atomic_kernel(const float* __restrict__ X, float* __restrict__ out) {
    const int p = blockIdx.x;
    int ti, tj;
    if (p < 384) {
        const int o = p >> 6;
        const int TI[6] = {0, 0, 0, 1, 1, 2};
        const int TJ[6] = {1, 2, 3, 2, 3, 3};
        ti = TI[o]; tj = TJ[o];
    } else {
        ti = tj = (p - 384) >> 6;
    }
    const int kbase = (p & 63) << 10;
    const bool diag = (ti == tj);

    __shared__ short As[128 * LDSS];
    __shared__ short Bs[128 * LDSS];

    const int t    = threadIdx.x;
    const int wave = t >> 6;
    const int lane = t & 63;
    const int wm   = wave & 1;
    const int wn   = wave >> 1;
    const int srow  = t >> 1;
    const int shalf = (t & 1) * 16;
    const float* pa = X + (size_t)(ti * 128 + srow) * HW + kbase + shalf;
    const float* pb = X + (size_t)(tj * 128 + srow) * HW + kbase + shalf;
    short* wa = As + srow * LDSS + shalf;
    short* wb = Bs + srow * LDSS + shalf;

    const int fm = lane & 15;
    const int kg = lane >> 4;
    int a_off[4], b_off[4];
#pragma unroll
    for (int i = 0; i < 4; ++i) {
        a_off[i] = (wm * 64 + i * 16 + fm) * LDSS + kg * 8;
        b_off[i] = (wn * 64 + i * 16 + fm) * LDSS + kg * 8;
    }
    const short* Bbase = diag ? As : Bs;

    f32x4 acc[4][4];
#pragma unroll
    for (int i = 0; i < 4; ++i)
#pragma unroll
        for (int j = 0; j < 4; ++j)
            acc[i][j] = (f32x4){0.f, 0.f, 0.f, 0.f};

    for (int it = 0; it < 32; ++it) {
        float4 a0 = *(const float4*)(pa + 0);
        float4 a1 = *(const float4*)(pa + 4);
        float4 a2 = *(const float4*)(pa + 8);
        float4 a3 = *(const float4*)(pa + 12);
        float4 b0, b1, b2, b3;
        if (!diag) {
            b0 = *(const float4*)(pb + 0);
            b1 = *(const float4*)(pb + 4);
            b2 = *(const float4*)(pb + 8);
            b3 = *(const float4*)(pb + 12);
        }
        bf16x8 va0 = cvt8(a0, a1), va1 = cvt8(a2, a3);
        bf16x8 vb0, vb1;
        if (!diag) { vb0 = cvt8(b0, b1); vb1 = cvt8(b2, b3); }
        __syncthreads();
        *(bf16x8*)(wa + 0) = va0;
        *(bf16x8*)(wa + 8) = va1;
        if (!diag) {
            *(bf16x8*)(wb + 0) = vb0;
            *(bf16x8*)(wb + 8) = vb1;
        }
        __syncthreads();
        bf16x8 af[4], bfr[4];
#pragma unroll
        for (int i = 0; i < 4; ++i) af[i]  = *(const bf16x8*)(As + a_off[i]);
#pragma unroll
        for (int j = 0; j < 4; ++j) bfr[j] = *(const bf16x8*)(Bbase + b_off[j]);
#pragma unroll
        for (int i = 0; i < 4; ++i)
#pragma unroll
            for (int j = 0; j < 4; ++j)
                acc[i][j] = __builtin_amdgcn_mfma_f32_16x16x32_bf16(
                    af[i], bfr[j], acc[i][j], 0, 0, 0);
        pa += 32;
        pb += 32;
    }

    const int orow0 = ti * 128 + wm * 64 + (lane >> 4) * 4;
    const int ocol0 = tj * 128 + wn * 64 + fm;
#pragma unroll
    for (int i = 0; i < 4; ++i)
#pragma unroll
        for (int j = 0; j < 4; ++j)
#pragma unroll
            for (int r = 0; r < 4; ++r)
                atomicAdd(out + (orow0 + i * 16 + r) * CDIM + ocol0 + j * 16,
                          acc[i][j][r]);
}

__global__ __launch_bounds__(256)
void mirror_kernel(float* __restrict__ out) {
    const int id = blockIdx.x * 256 + threadIdx.x;   // 0..262143
    const int r = id >> 9;
    const int c = id & 511;
    if ((r >> 7) > (c >> 7))
        out[id] = out[c * CDIM + r];
}

extern "C" void kernel_launch(void* const* d_in, const int* in_sizes, int n_in,
                              void* d_out, int out_size, void* d_ws, size_t ws_size,
                              hipStream_t stream) {
    const float* x = (const float*)d_in[0];
    float* out = (float*)d_out;
    const size_t ws_needed = 1280ull * TILE_ELEMS * sizeof(float);  // 83.9 MB

    if (d_ws != nullptr && ws_size >= ws_needed) {
        float* ws = (float*)d_ws;
        // reduce writes every out element exactly once -> no memset, no mirror
        gram_pair_kernel<<<dim3(768), dim3(256), 0, stream>>>(x, ws);
        reduce_kernel<<<dim3(320), dim3(128), 0, stream>>>(ws, out);
    } else {
        hipMemsetAsync(d_out, 0, (size_t)out_size * sizeof(float), stream);
        gram_atomic_kernel<<<dim3(640), dim3(256), 0, stream>>>(x, out);
        mirror_kernel<<<dim3(1024), dim3(256), 0, stream>>>(out);
    }
}